// Round 6
// baseline (258.172 us; speedup 1.0000x reference)
//
#include <hip/hip_runtime.h>
#include <math.h>

#define IMG_H 1024
#define IMG_W 1024
#define IMG_B 8
#define TPB 1024                   // 1024 thr * 1 px = one full row
#define RPB 32                     // output rows per band (y-halo eff: 32/42 = 76%)
#define BANDS (IMG_H / RPB)        // 32
#define NBLK (IMG_B * BANDS)       // 256 blocks = 1/CU = 16 waves/CU

__device__ __forceinline__ float sig2(float x) {   // sigmoid(2x) == sigmoid(x/EPS)
    return 1.0f / (1.0f + __expf(-2.0f * x));
}
__device__ __forceinline__ int imax(int a, int b) { return a > b ? a : b; }
__device__ __forceinline__ int imin(int a, int b) { return a < b ? a : b; }

// ---------------------------------------------------------------------------
// Depth-D row-pipelined kernel, 1 px/thread.
//   READQ: level-0 u = sig2(o - Tq(qin)); else u0 = sig2(o)  (q0 = 0).
//   FINAL: after Q-stage D, write out = 2*(o - Tq(q^D)) instead of q^D.
// All y-deps in per-thread register history; x-neighbor scalars cross threads
// via LDS. sp (p0 exchange) is shared across levels with level-parity double
// buffering: level l writes sp[l&1]; reuse of a buffer is 2 levels later,
// always separated by the intervening level's barrier.
// su (u rows) is per-level, row-parity double buffered.
// RPB=32: 85 row-steps per 32 output rows (vs 53/16 at RPB=16) -> 0.80x work.
// ---------------------------------------------------------------------------
template<int D, bool READQ, bool FINAL>
__global__ __launch_bounds__(TPB, 8) void k_pipe(const float* __restrict__ qin,
                                                 const float* __restrict__ vf,
                                                 const float* __restrict__ o,
                                                 float* __restrict__ out) {
    __shared__ float sp[2][TPB + 1];       // p0 boundary, level-parity
    __shared__ float su[D][2][TPB + 1];    // u rows, row-parity

    const int img = blockIdx.x / BANDS;
    const int r0  = (blockIdx.x % BANDS) * RPB;
    const int tid = threadIdx.x;
    const size_t ibase = (size_t)img * IMG_H * IMG_W;

    if (tid == 0) {
        sp[0][0] = 0.0f; sp[1][0] = 0.0f;
#pragma unroll
        for (int l = 0; l < D; ++l) { su[l][0][TPB] = 0.0f; su[l][1][TPB] = 0.0f; }
    }

    constexpr int HALO = FINAL ? 1 : 0;
    constexpr int NOH  = FINAL ? D + 1 : D;

    const int u0lo = imax(r0 - (D - 1) - HALO, 0);
    const int ylo  = READQ ? imax(r0 - D - HALO, 0) : u0lo;
    const int yend = r0 + RPB - 1 + D;
    const int yhi  = imin(yend, IMG_H - 1);

    float qc = 0.0f, qz = 0.0f;            // q^0 rows y, y-1
    float oh[NOH];                         // o rows y-l
    float v0h[D + 1], v1h[D + 1];          // vf rows y-l
    float uY[D], uZ[D];                    // u^l rows y-l, y-l-1
    float p1prev[D + 1];                   // p1 of q^l at previous row
    float qsave[D];                        // q^l held one step for level l+1
    float qvPrev = 0.0f;

#pragma unroll
    for (int l = 0; l < NOH; ++l) oh[l] = 0.0f;
#pragma unroll
    for (int l = 0; l <= D; ++l) { v0h[l] = 0.0f; v1h[l] = 0.0f; p1prev[l] = 0.0f; }
#pragma unroll
    for (int l = 0; l < D; ++l) { uY[l] = 0.0f; uZ[l] = 0.0f; qsave[l] = 0.0f; }

    const float* pQ = qin + ibase + (size_t)ylo * IMG_W + tid;
    const float* pO = o   + ibase + (size_t)ylo * IMG_W + tid;
    const float* pV = vf  + ((size_t)ylo * IMG_W + tid) * 2;

    for (int y = ylo; y <= yend; ++y) {
        // ---- shift row histories, then load row y ----
#pragma unroll
        for (int k = NOH - 1; k >= 1; --k) oh[k] = oh[k - 1];
#pragma unroll
        for (int k = D; k >= 1; --k) { v0h[k] = v0h[k - 1]; v1h[k] = v1h[k - 1]; }
        if constexpr (READQ) qz = qc;

        if (y <= yhi) {
            if constexpr (READQ) { qc = *pQ; pQ += IMG_W; }
            oh[0] = *pO; pO += IMG_W;
            float2 v2 = *(const float2*)pV; pV += 2 * IMG_W;
            v0h[0] = v2.x; v1h[0] = v2.y;
        } else {
            qc = 0.0f; oh[0] = 0.0f; v0h[0] = 0.0f; v1h[0] = 0.0f;
        }

        // ---- level 0 ----
        if constexpr (READQ) {
            float p0c = v0h[0] * qc;
            float p1c = v1h[0] * qc;
            sp[0][tid + 1] = p0c;
            __syncthreads();                       // barrier level 0
            if (y >= u0lo) {
                float pm1 = sp[0][tid];
                float nu = (y <= IMG_H - 1)
                    ? sig2(oh[0] - (p1c - p1prev[0] + p0c - pm1)) : 0.0f;
                uZ[0] = uY[0]; uY[0] = nu;
                su[0][y & 1][tid] = nu;
            }
            p1prev[0] = p1c;
        } else {
            float nu = (y <= IMG_H - 1) ? sig2(oh[0]) : 0.0f;
            uZ[0] = uY[0]; uY[0] = nu;
            su[0][y & 1][tid] = nu;
        }

        // ---- levels 1..D ----
#pragma unroll
        for (int l = 1; l <= D; ++l) {
            const int t = y - l;
            const int qlo = imax(r0 - (D - l) - HALO, 0);
            const bool qvalid = (t >= qlo) && (t <= IMG_H - 1);
            float qbase = (l == 1) ? (READQ ? qz : 0.0f) : qsave[l - 1];
            if (l >= 2) qsave[l - 1] = qvPrev;      // delayed save (read-before-write)
            float qv;
            if (qvalid) {
                const float uR = su[l - 1][t & 1][tid + 1];
                float gy = uY[l - 1] - uZ[l - 1];
                float gx = uR - uZ[l - 1];
                qv = fmaxf(qbase - 0.5f * (gy * v1h[l] + gx * v0h[l]), 0.0f);
            } else {
                qv = 0.0f;
            }

            if (l < D) {
                float p0p = v0h[l] * qv;
                float p1p = v1h[l] * qv;
                sp[l & 1][tid + 1] = p0p;
                __syncthreads();                   // barrier level l
                const int ulo = imax(r0 - (D - 1 - l) - HALO, 0);
                if (t >= ulo) {
                    float pm1 = sp[l & 1][tid];
                    float nu = (t <= IMG_H - 1)
                        ? sig2(oh[l] - (p1p - p1prev[l] + p0p - pm1)) : 0.0f;
                    uZ[l] = uY[l]; uY[l] = nu;
                    su[l][t & 1][tid] = nu;
                }
                p1prev[l] = p1p;
            } else {
                if constexpr (FINAL) {
                    float p0p = v0h[D] * qv;
                    float p1p = v1h[D] * qv;
                    sp[D & 1][tid + 1] = p0p;
                    __syncthreads();               // barrier final
                    if (t >= r0 && t < r0 + RPB) {
                        float pm1 = sp[D & 1][tid];
                        float Tq = p1p - p1prev[D] + p0p - pm1;
                        out[ibase + (size_t)t * IMG_W + tid] = 2.0f * (oh[D] - Tq);
                    }
                    p1prev[D] = p1p;
                } else {
                    if (t >= r0 && t < r0 + RPB)
                        out[ibase + (size_t)t * IMG_W + tid] = qv;
                }
            }
            qvPrev = qv;
        }
    }
}

extern "C" void kernel_launch(void* const* d_in, const int* in_sizes, int n_in,
                              void* d_out, int out_size, void* d_ws, size_t ws_size,
                              hipStream_t stream) {
    const float* o  = (const float*)d_in[0];
    const float* vf = (const float*)d_in[1];
    float* qA = (float*)d_ws;

    // iterations 1..5: o,vf -> q5  (no q read)
    k_pipe<5, false, false><<<NBLK, TPB, 0, stream>>>(o, vf, o, qA);
    // iterations 6..10 + final: q5,o,vf -> out
    k_pipe<5, true,  true ><<<NBLK, TPB, 0, stream>>>(qA, vf, o, (float*)d_out);
}